// Round 2
// baseline (380.231 us; speedup 1.0000x reference)
//
#include <hip/hip_runtime.h>
#include <cstdint>
#include <cstddef>

#define BPTS    131072
#define D_DIM   128
#define G_GR    128
#define NL      8
#define GD      (G_GR * D_DIM)       // 16384 floats = 64 KiB
#define NBLK    512                  // heavy-pass blocks: 2/CU, 16 waves/CU
#define TPB     512                  // 8 waves
#define PPB     (BPTS / NBLK)        // 256 contiguous points per block
#define PPW     (PPB / 8)            // 32 contiguous points per wave
#define DRB     16                   // dpart pre-reduce blocks

// Native LDS float atomic add (ds_add_f32, no CAS loop, no return).
__device__ __forceinline__ void lds_addf(float* p, float v) {
    __hip_atomic_fetch_add(p, v, __ATOMIC_RELAXED, __HIP_MEMORY_SCOPE_WORKGROUP);
}

// d += dpp_shifted(d); pure VALU, no DS pipe, no lgkmcnt.
// ctrl: 0x111/0x112/0x114/0x118 = row_shr 1/2/4/8, 0x142 = row_bcast15.
__device__ __forceinline__ float dpp_add(float d, const int ctrl) {
    int s;
    switch (ctrl) {   // ctrl must be an ICE for the builtin
    case 0x111: s = __builtin_amdgcn_update_dpp(0, __float_as_int(d), 0x111, 0xf, 0xf, true); break;
    case 0x112: s = __builtin_amdgcn_update_dpp(0, __float_as_int(d), 0x112, 0xf, 0xf, true); break;
    case 0x114: s = __builtin_amdgcn_update_dpp(0, __float_as_int(d), 0x114, 0xf, 0xf, true); break;
    case 0x118: s = __builtin_amdgcn_update_dpp(0, __float_as_int(d), 0x118, 0xf, 0xf, true); break;
    default:    s = __builtin_amdgcn_update_dpp(0, __float_as_int(d), 0x142, 0xf, 0xf, true); break;
    }
    return d + __int_as_float(s);
}

// ---------------------------------------------------------------------------
// k_centroid: stream X linearly; all 64 lanes ds_add their float4 into
// bins[g][*] (view0 lanes 0-31, view1 lanes 32-63 -> same group, same slots).
// Zero shuffles, zero divergence in the hot loop. Hist: one atomic per wave.
// ---------------------------------------------------------------------------
__global__ __launch_bounds__(TPB) void k_centroid(const float4* __restrict__ X4,
                                                  const int* __restrict__ sub,
                                                  const int* __restrict__ lab,
                                                  float* __restrict__ cpart,
                                                  int* __restrict__ hpart) {
    __shared__ float bins[GD];        // 64 KiB
    __shared__ int   hist[G_GR];
    int t = threadIdx.x, blk = blockIdx.x;
    int lane = t & 63, w = t >> 6;

    for (int i = t; i < GD; i += TPB) bins[i] = 0.f;
    if (t < G_GR) hist[t] = 0;

    int base = blk * PPB + w * PPW;           // wave's 32 contiguous points
    int pl = base + (lane & 31);
    int gv = sub[pl] * NL + lab[pl];          // lane l (and l+32) hold g(base+l)
    __syncthreads();

    if (lane < 32) atomicAdd(&hist[gv], 1);   // whole wave's hist in one op

    int col = (lane & 31) * 4;                // float slot within the row
    for (int it = 0; it < PPW / 8; ++it) {
        int p0 = base + it * 8;
        float4 x[8];
#pragma unroll
        for (int u = 0; u < 8; ++u)
            x[u] = X4[(size_t)(p0 + u) * 64 + lane];
#pragma unroll
        for (int u = 0; u < 8; ++u) {
            int g = __builtin_amdgcn_readlane(gv, it * 8 + u);  // uniform, SALU
            float* b = &bins[g * D_DIM + col];
            lds_addf(b + 0, x[u].x);
            lds_addf(b + 1, x[u].y);
            lds_addf(b + 2, x[u].z);
            lds_addf(b + 3, x[u].w);
        }
    }
    __syncthreads();
    for (int i = t; i < GD; i += TPB)
        cpart[(size_t)blk * GD + i] = bins[i];
    if (t < G_GR) hpart[blk * G_GR + t] = hist[t];
}

// ---------------------------------------------------------------------------
// k_reduce: centroid[g][d] = sum_b cpart[b][g][d] / (2n). 256 blocks:
// block = (g, half-of-D). Both halves compute n; half 0 publishes countsf.
// ---------------------------------------------------------------------------
__global__ __launch_bounds__(512) void k_reduce(const float* __restrict__ cpart,
                                                const int* __restrict__ hpart,
                                                float* __restrict__ centroid,
                                                float* __restrict__ countsf) {
    __shared__ float red[8][64];
    __shared__ int   hred[64];
    __shared__ float cf2s;
    int g = blockIdx.x >> 1, h = blockIdx.x & 1;
    int t = threadIdx.x;
    int dl = t & 63, bs = t >> 6;             // 8 b-slices x 64 lanes
    int d = h * 64 + dl;

    float acc = 0.f;
    for (int b = bs; b < NBLK; b += 8)
        acc += cpart[(size_t)b * GD + g * D_DIM + d];
    red[bs][dl] = acc;

    if (t < 64) {
        int hacc = 0;
        for (int b = t; b < NBLK; b += 64) hacc += hpart[b * G_GR + g];
        hred[t] = hacc;
    }
    __syncthreads();
    if (t == 0) {
        int n = 0;
        for (int i = 0; i < 64; ++i) n += hred[i];
        cf2s = 2.f * (float)n;
        if (h == 0) countsf[g] = cf2s;
    }
    __syncthreads();
    if (t < 64) {
        float v = 0.f;
#pragma unroll
        for (int r = 0; r < 8; ++r) v += red[r][t];
        float cf2 = cf2s;
        centroid[g * D_DIM + h * 64 + t] = (cf2 > 0.f) ? v / cf2 : 0.f;
    }
}

// ---------------------------------------------------------------------------
// k_distn: stream X linearly; centroid row read from LDS; per-point 32-lane
// reduction via DPP (VALU-only): lane31 = view0 sum, lane63 = view1 sum.
// Per-point result accumulates in a register (lane == point slot); one
// 32-lane ds_add per wave at the end. Zero shuffles, zero per-point atomics.
// ---------------------------------------------------------------------------
__global__ __launch_bounds__(TPB) void k_distn(const float4* __restrict__ X4,
                                               const int* __restrict__ sub,
                                               const int* __restrict__ lab,
                                               const float* __restrict__ centroid,
                                               float* __restrict__ dpart) {
    __shared__ float cen[GD];         // 64 KiB
    __shared__ float dbin[G_GR];
    int t = threadIdx.x, blk = blockIdx.x;
    int lane = t & 63, w = t >> 6;

    for (int i = t; i < GD; i += TPB) cen[i] = centroid[i];
    if (t < G_GR) dbin[t] = 0.f;

    int base = blk * PPB + w * PPW;
    int pl = base + (lane & 31);
    int gv = sub[pl] * NL + lab[pl];
    __syncthreads();

    const float4* cen4 = (const float4*)cen;
    int ci = lane & 31;

    float dacc = 0.f;
    for (int it = 0; it < PPW / 8; ++it) {
        int p0 = base + it * 8;
        float4 x[8];
#pragma unroll
        for (int u = 0; u < 8; ++u)
            x[u] = X4[(size_t)(p0 + u) * 64 + lane];
#pragma unroll
        for (int u = 0; u < 8; ++u) {
            int g = __builtin_amdgcn_readlane(gv, it * 8 + u);
            float4 c = cen4[g * 32 + ci];   // lanes l, l+32 same addr: broadcast
            float dx = x[u].x - c.x, dy = x[u].y - c.y;
            float dz = x[u].z - c.z, dw = x[u].w - c.w;
            float d = dx * dx + dy * dy + dz * dz + dw * dw;
            d = dpp_add(d, 0x111);          // row_shr:1
            d = dpp_add(d, 0x112);          // row_shr:2
            d = dpp_add(d, 0x114);          // row_shr:4
            d = dpp_add(d, 0x118);          // row_shr:8  -> lane15/31/47/63 = 16-sums
            d = dpp_add(d, 0x142);          // row_bcast15 -> lane31/63 = 32-sums
            float s0 = __int_as_float(__builtin_amdgcn_readlane(__float_as_int(d), 31));
            float s1 = __int_as_float(__builtin_amdgcn_readlane(__float_as_int(d), 63));
            float st = sqrtf(sqrtf(s0)) + sqrtf(sqrtf(s1));  // uniform VALU
            if (lane == it * 8 + u) dacc += st;              // point -> own lane
        }
    }
    if (lane < 32) lds_addf(&dbin[gv], dacc);   // one scatter per wave
    __syncthreads();
    if (t < G_GR) dpart[blk * G_GR + t] = dbin[t];
}

// ---------------------------------------------------------------------------
// k_dred: fold 512 dpart rows to 16 (coalesced) so k_final stays cheap.
// ---------------------------------------------------------------------------
__global__ __launch_bounds__(256) void k_dred(const float* __restrict__ dpart,
                                              float* __restrict__ dmid) {
    __shared__ float red[2][G_GR];
    int t = threadIdx.x, blk = blockIdx.x;
    int d = t & 127, h = t >> 7;
    int b0 = blk * (NBLK / DRB);
    float acc = 0.f;
    for (int b = b0 + h; b < b0 + NBLK / DRB; b += 2)
        acc += dpart[b * G_GR + d];
    red[h][d] = acc;
    __syncthreads();
    if (t < G_GR) dmid[blk * G_GR + t] = red[0][t] + red[1][t];
}

// ---------------------------------------------------------------------------
// k_final: single block, 128 threads (thread t = group t).
// ---------------------------------------------------------------------------
__global__ __launch_bounds__(128) void k_final(const float* __restrict__ dmid,
                                               const float* __restrict__ countsf,
                                               const float* __restrict__ centroid,
                                               float* __restrict__ out) {
    __shared__ float srt[G_GR];
    __shared__ float red[G_GR];
    __shared__ float coc[D_DIM];
    int t = threadIdx.x;

    float ds = 0.f;
    for (int b = 0; b < DRB; ++b) ds += dmid[b * G_GR + t];
    float cnt  = countsf[t];
    float dens = (cnt > 1.f) ? (ds / cnt) / logf(cnt + 10.f) : 0.f;

    red[t] = dens;
    __syncthreads();
    for (int s = 64; s > 0; s >>= 1) {
        if (t < s) red[t] = fmaxf(red[t], red[t + s]);
        __syncthreads();
    }
    float dmax = red[0];
    __syncthreads();
    if (!(cnt > 1.f)) dens = dmax;

    // bitonic sort ascending
    srt[t] = dens;
    __syncthreads();
    for (int k = 2; k <= G_GR; k <<= 1) {
        for (int j = k >> 1; j > 0; j >>= 1) {
            int ixj = t ^ j;
            if (ixj > t) {
                float a = srt[t], b = srt[ixj];
                bool up = ((t & k) == 0);
                if ((a > b) == up) { srt[t] = b; srt[ixj] = a; }
            }
            __syncthreads();
        }
    }
    double p10 = 0.10 * 127.0, p90 = 0.90 * 127.0;
    int   i10 = (int)p10,           i90 = (int)p90;
    float f10 = (float)(p10 - i10), f90 = (float)(p90 - i90);
    float lo = srt[i10] + f10 * (srt[i10 + 1] - srt[i10]);
    float hi = srt[i90] + f90 * (srt[i90 + 1] - srt[i90]);
    dens = fminf(fmaxf(dens, lo), hi);

    red[t] = dens;
    __syncthreads();
    for (int s = 64; s > 0; s >>= 1) {
        if (t < s) red[t] += red[t + s];
        __syncthreads();
    }
    float dmean = red[0] / 128.f;
    __syncthreads();
    dens = 0.1f * dens / dmean;

    float cs = 0.f;
    for (int g = 0; g < G_GR; ++g) cs += centroid[g * D_DIM + t];
    coc[t] = cs / 128.f;
    __syncthreads();

    float dot = 0.f;
    for (int d = 0; d < D_DIM; ++d) dot += centroid[t * D_DIM + d] * coc[d];
    float sim = expf(dot / dens);

    red[t] = sim;
    __syncthreads();
    for (int s = 64; s > 0; s >>= 1) {
        if (t < s) red[t] = fmaxf(red[t], red[t + s]);
        __syncthreads();
    }
    float smax = red[0];
    __syncthreads();
    red[t] = sim - smax;
    __syncthreads();
    for (int s = 64; s > 0; s >>= 1) {
        if (t < s) red[t] += red[t + s];
        __syncthreads();
    }
    if (t == 0) out[0] = -(red[0] / 128.f);
}

// ---------------------------------------------------------------------------
extern "C" void kernel_launch(void* const* d_in, const int* in_sizes, int n_in,
                              void* d_out, int out_size, void* d_ws, size_t ws_size,
                              hipStream_t stream) {
    const float4* X4      = (const float4*)d_in[0];
    const int*    subject = (const int*)d_in[1];
    const int*    labels  = (const int*)d_in[2];
    float*        out     = (float*)d_out;
    char*         ws      = (char*)d_ws;

    size_t o = 0;
    float* cpart    = (float*)(ws + o); o += (size_t)NBLK * GD * 4;     // 32 MiB
    int*   hpart    = (int*)(ws + o);   o += (size_t)NBLK * G_GR * 4;   // 256 KiB
    float* centroid = (float*)(ws + o); o += (size_t)GD * 4;            // 64 KiB
    float* countsf  = (float*)(ws + o); o += 512;
    float* dpart    = (float*)(ws + o); o += (size_t)NBLK * G_GR * 4;   // 256 KiB
    float* dmid     = (float*)(ws + o); o += (size_t)DRB * G_GR * 4;    // 8 KiB

    k_centroid<<<NBLK, TPB, 0, stream>>>(X4, subject, labels, cpart, hpart);
    k_reduce  <<<G_GR * 2, 512, 0, stream>>>(cpart, hpart, centroid, countsf);
    k_distn   <<<NBLK, TPB, 0, stream>>>(X4, subject, labels, centroid, dpart);
    k_dred    <<<DRB, 256, 0, stream>>>(dpart, dmid);
    k_final   <<<1, 128, 0, stream>>>(dmid, countsf, centroid, out);
}

// Round 3
// 293.603 us; speedup vs baseline: 1.2951x; 1.2951x over previous
//
#include <hip/hip_runtime.h>
#include <cstdint>
#include <cstddef>

#define BPTS    131072
#define D_DIM   128
#define G_GR    128
#define NL      8
#define GD      (G_GR * D_DIM)       // 16384 floats = 64 KiB
#define NBLK    512                  // heavy-pass blocks: 2/CU, 16 waves/CU
#define TPB     512                  // 8 waves
#define PPB     (BPTS / NBLK)        // 256 contiguous points per block
#define PPW     (PPB / 8)            // 32 contiguous points per wave
#define DRB     16                   // dpart pre-reduce blocks

// d += dpp_shifted(d); pure VALU, no DS pipe.
// 0x111/0x112/0x114/0x118 = row_shr 1/2/4/8; 0x142/0x143 = row_bcast 15/31.
__device__ __forceinline__ float dpp_add(float d, const int ctrl) {
    int s;
    switch (ctrl) {   // ctrl must be an ICE for the builtin
    case 0x111: s = __builtin_amdgcn_update_dpp(0, __float_as_int(d), 0x111, 0xf, 0xf, true); break;
    case 0x112: s = __builtin_amdgcn_update_dpp(0, __float_as_int(d), 0x112, 0xf, 0xf, true); break;
    case 0x114: s = __builtin_amdgcn_update_dpp(0, __float_as_int(d), 0x114, 0xf, 0xf, true); break;
    case 0x118: s = __builtin_amdgcn_update_dpp(0, __float_as_int(d), 0x118, 0xf, 0xf, true); break;
    case 0x142: s = __builtin_amdgcn_update_dpp(0, __float_as_int(d), 0x142, 0xf, 0xf, true); break;
    default:    s = __builtin_amdgcn_update_dpp(0, __float_as_int(d), 0x143, 0xf, 0xf, true); break;
    }
    return d + __int_as_float(s);
}

// full 64-lane sum -> result in lane 63
__device__ __forceinline__ float sum64(float d) {
    d = dpp_add(d, 0x111);
    d = dpp_add(d, 0x112);
    d = dpp_add(d, 0x114);
    d = dpp_add(d, 0x118);   // lane 15/31/47/63 hold 16-lane sums
    d = dpp_add(d, 0x142);   // lane 31/63 hold 32-lane sums
    d = dpp_add(d, 0x143);   // lane 63 holds 64-lane sum
    return d;
}

// ---------------------------------------------------------------------------
// k_centroid: strided scalar loads -> lane l holds dims {l, l+64} of both
// views. View-fold = per-lane VALU add. Binning = 2 ds_adds per point, each
// 64 consecutive words (2/bank = free), ZERO same-address lanes in any
// instruction. Hist: one 32-lane atomic per wave.
// ---------------------------------------------------------------------------
__global__ __launch_bounds__(TPB) void k_centroid(const float* __restrict__ Xf,
                                                  const int* __restrict__ sub,
                                                  const int* __restrict__ lab,
                                                  float* __restrict__ cpart,
                                                  int* __restrict__ hpart) {
    __shared__ float bins[GD];        // 64 KiB
    __shared__ int   hist[G_GR];
    int t = threadIdx.x, blk = blockIdx.x;
    int lane = t & 63, w = t >> 6;

    for (int i = t; i < GD; i += TPB) bins[i] = 0.f;
    if (t < G_GR) hist[t] = 0;

    int base = blk * PPB + w * PPW;           // wave's 32 contiguous points
    int pl = base + (lane & 31);
    int gv = sub[pl] * NL + lab[pl];          // lanes l and l+32 hold g(base+l)
    __syncthreads();

    if (lane < 32) atomicAdd(&hist[gv], 1);   // whole wave's hist in one op

    for (int it = 0; it < PPW / 8; ++it) {
        int p0 = base + it * 8;
        float x0[8], x1[8], x2[8], x3[8];
#pragma unroll
        for (int u = 0; u < 8; ++u) {
            const float* r = Xf + (size_t)(p0 + u) * 256;
            x0[u] = r[lane];                  // view0 dim l
            x1[u] = r[64  + lane];            // view0 dim 64+l
            x2[u] = r[128 + lane];            // view1 dim l
            x3[u] = r[192 + lane];            // view1 dim 64+l
        }
#pragma unroll
        for (int u = 0; u < 8; ++u) {
            int g = __builtin_amdgcn_readlane(gv, it * 8 + u);  // uniform
            float vlo = x0[u] + x2[u];        // fold views, per-lane
            float vhi = x1[u] + x3[u];
            atomicAdd(&bins[g * D_DIM + lane],      vlo);
            atomicAdd(&bins[g * D_DIM + 64 + lane], vhi);
        }
    }
    __syncthreads();
    for (int i = t; i < GD; i += TPB)
        cpart[(size_t)blk * GD + i] = bins[i];
    if (t < G_GR) hpart[blk * G_GR + t] = hist[t];
}

// ---------------------------------------------------------------------------
// k_reduce: centroid[g][d] = sum_b cpart[b][g][d] / (2n). 256 blocks:
// block = (g, half-of-D). Both halves compute n; half 0 publishes countsf.
// ---------------------------------------------------------------------------
__global__ __launch_bounds__(512) void k_reduce(const float* __restrict__ cpart,
                                                const int* __restrict__ hpart,
                                                float* __restrict__ centroid,
                                                float* __restrict__ countsf) {
    __shared__ float red[8][64];
    __shared__ int   hred[64];
    __shared__ float cf2s;
    int g = blockIdx.x >> 1, h = blockIdx.x & 1;
    int t = threadIdx.x;
    int dl = t & 63, bs = t >> 6;             // 8 b-slices x 64 lanes
    int d = h * 64 + dl;

    float acc = 0.f;
    for (int b = bs; b < NBLK; b += 8)
        acc += cpart[(size_t)b * GD + g * D_DIM + d];
    red[bs][dl] = acc;

    if (t < 64) {
        int hacc = 0;
        for (int b = t; b < NBLK; b += 64) hacc += hpart[b * G_GR + g];
        hred[t] = hacc;
    }
    __syncthreads();
    if (t == 0) {
        int n = 0;
        for (int i = 0; i < 64; ++i) n += hred[i];
        cf2s = 2.f * (float)n;
        if (h == 0) countsf[g] = cf2s;
    }
    __syncthreads();
    if (t < 64) {
        float v = 0.f;
#pragma unroll
        for (int r = 0; r < 8; ++r) v += red[r][t];
        float cf2 = cf2s;
        centroid[g * D_DIM + h * 64 + t] = (cf2 > 0.f) ? v / cf2 : 0.f;
    }
}

// ---------------------------------------------------------------------------
// k_distn: same strided load; centroid pair via two consecutive LDS reads
// (conflict-free); per-point per-view ||x-c||^2 via 64-lane DPP sum (VALU
// pipe only); result accumulates in the point's own lane; one 32-lane
// ds_add per wave at the end.
// ---------------------------------------------------------------------------
__global__ __launch_bounds__(TPB) void k_distn(const float* __restrict__ Xf,
                                               const int* __restrict__ sub,
                                               const int* __restrict__ lab,
                                               const float* __restrict__ centroid,
                                               float* __restrict__ dpart) {
    __shared__ float cen[GD];         // 64 KiB
    __shared__ float dbin[G_GR];
    int t = threadIdx.x, blk = blockIdx.x;
    int lane = t & 63, w = t >> 6;

    for (int i = t; i < GD; i += TPB) cen[i] = centroid[i];
    if (t < G_GR) dbin[t] = 0.f;

    int base = blk * PPB + w * PPW;
    int pl = base + (lane & 31);
    int gv = sub[pl] * NL + lab[pl];
    __syncthreads();

    float dacc = 0.f;
    for (int it = 0; it < PPW / 8; ++it) {
        int p0 = base + it * 8;
        float x0[8], x1[8], x2[8], x3[8];
#pragma unroll
        for (int u = 0; u < 8; ++u) {
            const float* r = Xf + (size_t)(p0 + u) * 256;
            x0[u] = r[lane];
            x1[u] = r[64  + lane];
            x2[u] = r[128 + lane];
            x3[u] = r[192 + lane];
        }
#pragma unroll
        for (int u = 0; u < 8; ++u) {
            int g = __builtin_amdgcn_readlane(gv, it * 8 + u);
            float c_lo = cen[g * D_DIM + lane];
            float c_hi = cen[g * D_DIM + 64 + lane];
            float e0 = x0[u] - c_lo, e1 = x1[u] - c_hi;   // view0
            float e2 = x2[u] - c_lo, e3 = x3[u] - c_hi;   // view1
            float d0 = sum64(e0 * e0 + e1 * e1);
            float d1 = sum64(e2 * e2 + e3 * e3);
            float s0 = __int_as_float(__builtin_amdgcn_readlane(__float_as_int(d0), 63));
            float s1 = __int_as_float(__builtin_amdgcn_readlane(__float_as_int(d1), 63));
            float st = sqrtf(sqrtf(s0)) + sqrtf(sqrtf(s1));
            if (lane == it * 8 + u) dacc += st;           // point -> own lane
        }
    }
    if (lane < 32) atomicAdd(&dbin[gv], dacc);   // once per wave
    __syncthreads();
    if (t < G_GR) dpart[blk * G_GR + t] = dbin[t];
}

// ---------------------------------------------------------------------------
// k_dred: fold 512 dpart rows to 16 (coalesced) so k_final stays cheap.
// ---------------------------------------------------------------------------
__global__ __launch_bounds__(256) void k_dred(const float* __restrict__ dpart,
                                              float* __restrict__ dmid) {
    __shared__ float red[2][G_GR];
    int t = threadIdx.x, blk = blockIdx.x;
    int d = t & 127, h = t >> 7;
    int b0 = blk * (NBLK / DRB);
    float acc = 0.f;
    for (int b = b0 + h; b < b0 + NBLK / DRB; b += 2)
        acc += dpart[b * G_GR + d];
    red[h][d] = acc;
    __syncthreads();
    if (t < G_GR) dmid[blk * G_GR + t] = red[0][t] + red[1][t];
}

// ---------------------------------------------------------------------------
// k_final: single block, 128 threads (thread t = group t).
// ---------------------------------------------------------------------------
__global__ __launch_bounds__(128) void k_final(const float* __restrict__ dmid,
                                               const float* __restrict__ countsf,
                                               const float* __restrict__ centroid,
                                               float* __restrict__ out) {
    __shared__ float srt[G_GR];
    __shared__ float red[G_GR];
    __shared__ float coc[D_DIM];
    int t = threadIdx.x;

    float ds = 0.f;
    for (int b = 0; b < DRB; ++b) ds += dmid[b * G_GR + t];
    float cnt  = countsf[t];
    float dens = (cnt > 1.f) ? (ds / cnt) / logf(cnt + 10.f) : 0.f;

    red[t] = dens;
    __syncthreads();
    for (int s = 64; s > 0; s >>= 1) {
        if (t < s) red[t] = fmaxf(red[t], red[t + s]);
        __syncthreads();
    }
    float dmax = red[0];
    __syncthreads();
    if (!(cnt > 1.f)) dens = dmax;

    // bitonic sort ascending
    srt[t] = dens;
    __syncthreads();
    for (int k = 2; k <= G_GR; k <<= 1) {
        for (int j = k >> 1; j > 0; j >>= 1) {
            int ixj = t ^ j;
            if (ixj > t) {
                float a = srt[t], b = srt[ixj];
                bool up = ((t & k) == 0);
                if ((a > b) == up) { srt[t] = b; srt[ixj] = a; }
            }
            __syncthreads();
        }
    }
    double p10 = 0.10 * 127.0, p90 = 0.90 * 127.0;
    int   i10 = (int)p10,           i90 = (int)p90;
    float f10 = (float)(p10 - i10), f90 = (float)(p90 - i90);
    float lo = srt[i10] + f10 * (srt[i10 + 1] - srt[i10]);
    float hi = srt[i90] + f90 * (srt[i90 + 1] - srt[i90]);
    dens = fminf(fmaxf(dens, lo), hi);

    red[t] = dens;
    __syncthreads();
    for (int s = 64; s > 0; s >>= 1) {
        if (t < s) red[t] += red[t + s];
        __syncthreads();
    }
    float dmean = red[0] / 128.f;
    __syncthreads();
    dens = 0.1f * dens / dmean;

    float cs = 0.f;
    for (int g = 0; g < G_GR; ++g) cs += centroid[g * D_DIM + t];
    coc[t] = cs / 128.f;
    __syncthreads();

    float dot = 0.f;
    for (int d = 0; d < D_DIM; ++d) dot += centroid[t * D_DIM + d] * coc[d];
    float sim = expf(dot / dens);

    red[t] = sim;
    __syncthreads();
    for (int s = 64; s > 0; s >>= 1) {
        if (t < s) red[t] = fmaxf(red[t], red[t + s]);
        __syncthreads();
    }
    float smax = red[0];
    __syncthreads();
    red[t] = sim - smax;
    __syncthreads();
    for (int s = 64; s > 0; s >>= 1) {
        if (t < s) red[t] += red[t + s];
        __syncthreads();
    }
    if (t == 0) out[0] = -(red[0] / 128.f);
}

// ---------------------------------------------------------------------------
extern "C" void kernel_launch(void* const* d_in, const int* in_sizes, int n_in,
                              void* d_out, int out_size, void* d_ws, size_t ws_size,
                              hipStream_t stream) {
    const float*  Xf      = (const float*)d_in[0];
    const int*    subject = (const int*)d_in[1];
    const int*    labels  = (const int*)d_in[2];
    float*        out     = (float*)d_out;
    char*         ws      = (char*)d_ws;

    size_t o = 0;
    float* cpart    = (float*)(ws + o); o += (size_t)NBLK * GD * 4;     // 32 MiB
    int*   hpart    = (int*)(ws + o);   o += (size_t)NBLK * G_GR * 4;   // 256 KiB
    float* centroid = (float*)(ws + o); o += (size_t)GD * 4;            // 64 KiB
    float* countsf  = (float*)(ws + o); o += 512;
    float* dpart    = (float*)(ws + o); o += (size_t)NBLK * G_GR * 4;   // 256 KiB
    float* dmid     = (float*)(ws + o); o += (size_t)DRB * G_GR * 4;    // 8 KiB

    k_centroid<<<NBLK, TPB, 0, stream>>>(Xf, subject, labels, cpart, hpart);
    k_reduce  <<<G_GR * 2, 512, 0, stream>>>(cpart, hpart, centroid, countsf);
    k_distn   <<<NBLK, TPB, 0, stream>>>(Xf, subject, labels, centroid, dpart);
    k_dred    <<<DRB, 256, 0, stream>>>(dpart, dmid);
    k_final   <<<1, 128, 0, stream>>>(dmid, countsf, centroid, out);
}

// Round 4
// 271.422 us; speedup vs baseline: 1.4009x; 1.0817x over previous
//
#include <hip/hip_runtime.h>
#include <cstdint>
#include <cstddef>

#define BPTS    131072
#define D_DIM   128
#define G_GR    128
#define NL      8
#define GD      (G_GR * D_DIM)       // 16384 floats = 64 KiB
#define NBLK    512                  // heavy-pass blocks: 2/CU
#define TPB     1024                 // 16 waves -> 32 waves/CU
#define PPB     (BPTS / NBLK)        // 256 contiguous points per block
#define GPW     (G_GR / (TPB / 64))  // 8 groups per wave
#define DRB     16                   // dpart pre-reduce blocks

// d += dpp_shifted(d); pure VALU, no DS pipe.
__device__ __forceinline__ float dpp_add(float d, const int ctrl) {
    int s;
    switch (ctrl) {   // ctrl must be an ICE for the builtin
    case 0x111: s = __builtin_amdgcn_update_dpp(0, __float_as_int(d), 0x111, 0xf, 0xf, true); break;
    case 0x112: s = __builtin_amdgcn_update_dpp(0, __float_as_int(d), 0x112, 0xf, 0xf, true); break;
    case 0x114: s = __builtin_amdgcn_update_dpp(0, __float_as_int(d), 0x114, 0xf, 0xf, true); break;
    case 0x118: s = __builtin_amdgcn_update_dpp(0, __float_as_int(d), 0x118, 0xf, 0xf, true); break;
    case 0x142: s = __builtin_amdgcn_update_dpp(0, __float_as_int(d), 0x142, 0xf, 0xf, true); break;
    default:    s = __builtin_amdgcn_update_dpp(0, __float_as_int(d), 0x143, 0xf, 0xf, true); break;
    }
    return d + __int_as_float(s);
}

// full 64-lane sum -> result valid in lane 63
__device__ __forceinline__ float sum64(float d) {
    d = dpp_add(d, 0x111);
    d = dpp_add(d, 0x112);
    d = dpp_add(d, 0x114);
    d = dpp_add(d, 0x118);   // lane 15/31/47/63 hold 16-lane sums
    d = dpp_add(d, 0x142);   // lane 31/63 hold 32-lane sums
    d = dpp_add(d, 0x143);   // lane 63 holds 64-lane sum
    return d;
}

// Per-block group bucketing: hist + Hillis-Steele prefix + scatter of local
// point indices. Costs ~256 int atomic-lanes (vs 65K float lanes it replaces).
__device__ __forceinline__ void build_lists(const int* __restrict__ sub,
                                            const int* __restrict__ lab,
                                            int pbase, int t,
                                            int* glist, int* goff,
                                            int* hist, int* cursor, int* scan) {
    if (t < G_GR) hist[t] = 0;
    __syncthreads();
    int myg = -1;
    if (t < PPB) {
        myg = sub[pbase + t] * NL + lab[pbase + t];
        atomicAdd(&hist[myg], 1);
    }
    __syncthreads();
    if (t < G_GR) scan[t] = hist[t];
    __syncthreads();
    for (int s = 1; s < G_GR; s <<= 1) {
        int v = 0;
        if (t < G_GR) { v = scan[t]; if (t >= s) v += scan[t - s]; }
        __syncthreads();
        if (t < G_GR) scan[t] = v;
        __syncthreads();
    }
    if (t < G_GR) { goff[t] = scan[t] - hist[t]; cursor[t] = scan[t] - hist[t]; }
    __syncthreads();
    if (t < PPB) {
        int pos = atomicAdd(&cursor[myg], 1);
        glist[pos] = t;
    }
    __syncthreads();
}

// ---------------------------------------------------------------------------
// k_centroid: group-major register accumulation. Wave w owns groups
// [w*GPW, (w+1)*GPW); per group, iterate its bucketed points with coalesced
// float2 loads (lane l <-> dims 2l,2l+1), fold views per-lane, accumulate in
// a float2 REGISTER, one coalesced 512B store per group. Zero LDS atomics
// in the hot path.
// ---------------------------------------------------------------------------
__global__ __launch_bounds__(TPB) void k_centroid(const float* __restrict__ Xf,
                                                  const int* __restrict__ sub,
                                                  const int* __restrict__ lab,
                                                  float* __restrict__ cpart,
                                                  int* __restrict__ hpart) {
    __shared__ int glist[PPB];
    __shared__ int goff[G_GR];
    __shared__ int hist[G_GR];
    __shared__ int cursor[G_GR];
    __shared__ int scan[G_GR];
    int t = threadIdx.x, blk = blockIdx.x;
    int lane = t & 63, w = t >> 6;
    int pbase = blk * PPB;

    build_lists(sub, lab, pbase, t, glist, goff, hist, cursor, scan);
    if (t < G_GR) hpart[blk * G_GR + t] = hist[t];

    for (int gi = 0; gi < GPW; ++gi) {
        int g = w * GPW + gi;
        int s = goff[g], n = hist[g];
        float ax = 0.f, ay = 0.f;
        int k = 0;
        for (; k + 2 <= n; k += 2) {                 // unroll-2 for MLP
            int p0 = pbase + glist[s + k];
            int p1 = pbase + glist[s + k + 1];
            const float* r0 = Xf + (size_t)p0 * 256;
            const float* r1 = Xf + (size_t)p1 * 256;
            float2 a0 = *(const float2*)(r0 + 2 * lane);
            float2 b0 = *(const float2*)(r0 + 128 + 2 * lane);
            float2 a1 = *(const float2*)(r1 + 2 * lane);
            float2 b1 = *(const float2*)(r1 + 128 + 2 * lane);
            ax += (a0.x + b0.x) + (a1.x + b1.x);
            ay += (a0.y + b0.y) + (a1.y + b1.y);
        }
        if (k < n) {
            int p = pbase + glist[s + k];
            const float* r = Xf + (size_t)p * 256;
            float2 a = *(const float2*)(r + 2 * lane);
            float2 b = *(const float2*)(r + 128 + 2 * lane);
            ax += a.x + b.x;
            ay += a.y + b.y;
        }
        float2 o; o.x = ax; o.y = ay;
        *(float2*)(cpart + (size_t)blk * GD + (size_t)g * D_DIM + 2 * lane) = o;
    }
}

// ---------------------------------------------------------------------------
// k_reduce: centroid[g][d] = sum_b cpart[b][g][d] / (2n). 256 blocks:
// block = (g, half-of-D). Both halves compute n; half 0 publishes countsf.
// ---------------------------------------------------------------------------
__global__ __launch_bounds__(512) void k_reduce(const float* __restrict__ cpart,
                                                const int* __restrict__ hpart,
                                                float* __restrict__ centroid,
                                                float* __restrict__ countsf) {
    __shared__ float red[8][64];
    __shared__ int   hred[64];
    __shared__ float cf2s;
    int g = blockIdx.x >> 1, h = blockIdx.x & 1;
    int t = threadIdx.x;
    int dl = t & 63, bs = t >> 6;             // 8 b-slices x 64 lanes
    int d = h * 64 + dl;

    float acc = 0.f;
    for (int b = bs; b < NBLK; b += 8)
        acc += cpart[(size_t)b * GD + g * D_DIM + d];
    red[bs][dl] = acc;

    if (t < 64) {
        int hacc = 0;
        for (int b = t; b < NBLK; b += 64) hacc += hpart[b * G_GR + g];
        hred[t] = hacc;
    }
    __syncthreads();
    if (t == 0) {
        int n = 0;
        for (int i = 0; i < 64; ++i) n += hred[i];
        cf2s = 2.f * (float)n;
        if (h == 0) countsf[g] = cf2s;
    }
    __syncthreads();
    if (t < 64) {
        float v = 0.f;
#pragma unroll
        for (int r = 0; r < 8; ++r) v += red[r][t];
        float cf2 = cf2s;
        centroid[g * D_DIM + h * 64 + t] = (cf2 > 0.f) ? v / cf2 : 0.f;
    }
}

// ---------------------------------------------------------------------------
// k_distn: same group-major structure. Centroid row loaded ONCE per group
// (was per point); per point: 2 coalesced float2 loads, two independent
// 64-lane DPP sums (VALU pipe), sqrt(sqrt()) accumulated in lane 63's
// register; one plain store per group. Zero LDS atomics, zero readlanes.
// ---------------------------------------------------------------------------
__global__ __launch_bounds__(TPB) void k_distn(const float* __restrict__ Xf,
                                               const int* __restrict__ sub,
                                               const int* __restrict__ lab,
                                               const float* __restrict__ centroid,
                                               float* __restrict__ dpart) {
    __shared__ int glist[PPB];
    __shared__ int goff[G_GR];
    __shared__ int hist[G_GR];
    __shared__ int cursor[G_GR];
    __shared__ int scan[G_GR];
    int t = threadIdx.x, blk = blockIdx.x;
    int lane = t & 63, w = t >> 6;
    int pbase = blk * PPB;

    build_lists(sub, lab, pbase, t, glist, goff, hist, cursor, scan);

    for (int gi = 0; gi < GPW; ++gi) {
        int g = w * GPW + gi;
        int s = goff[g], n = hist[g];
        float2 c = *(const float2*)(centroid + (size_t)g * D_DIM + 2 * lane);
        float sacc = 0.f;
        for (int k = 0; k < n; ++k) {
            int p = pbase + glist[s + k];
            const float* r = Xf + (size_t)p * 256;
            float2 a = *(const float2*)(r + 2 * lane);        // view0
            float2 b = *(const float2*)(r + 128 + 2 * lane);  // view1
            float e0 = a.x - c.x, e1 = a.y - c.y;
            float f0 = b.x - c.x, f1 = b.y - c.y;
            float d0 = sum64(e0 * e0 + e1 * e1);   // two independent DPP chains
            float d1 = sum64(f0 * f0 + f1 * f1);
            sacc += sqrtf(sqrtf(d0)) + sqrtf(sqrtf(d1));      // valid in lane 63
        }
        if (lane == 63) dpart[blk * G_GR + g] = sacc;
    }
}

// ---------------------------------------------------------------------------
// k_dred: fold 512 dpart rows to 16 (coalesced) so k_final stays cheap.
// ---------------------------------------------------------------------------
__global__ __launch_bounds__(256) void k_dred(const float* __restrict__ dpart,
                                              float* __restrict__ dmid) {
    __shared__ float red[2][G_GR];
    int t = threadIdx.x, blk = blockIdx.x;
    int d = t & 127, h = t >> 7;
    int b0 = blk * (NBLK / DRB);
    float acc = 0.f;
    for (int b = b0 + h; b < b0 + NBLK / DRB; b += 2)
        acc += dpart[b * G_GR + d];
    red[h][d] = acc;
    __syncthreads();
    if (t < G_GR) dmid[blk * G_GR + t] = red[0][t] + red[1][t];
}

// ---------------------------------------------------------------------------
// k_final: single block, 128 threads (thread t = group t).
// ---------------------------------------------------------------------------
__global__ __launch_bounds__(128) void k_final(const float* __restrict__ dmid,
                                               const float* __restrict__ countsf,
                                               const float* __restrict__ centroid,
                                               float* __restrict__ out) {
    __shared__ float srt[G_GR];
    __shared__ float red[G_GR];
    __shared__ float coc[D_DIM];
    int t = threadIdx.x;

    float ds = 0.f;
    for (int b = 0; b < DRB; ++b) ds += dmid[b * G_GR + t];
    float cnt  = countsf[t];
    float dens = (cnt > 1.f) ? (ds / cnt) / logf(cnt + 10.f) : 0.f;

    red[t] = dens;
    __syncthreads();
    for (int s = 64; s > 0; s >>= 1) {
        if (t < s) red[t] = fmaxf(red[t], red[t + s]);
        __syncthreads();
    }
    float dmax = red[0];
    __syncthreads();
    if (!(cnt > 1.f)) dens = dmax;

    // bitonic sort ascending
    srt[t] = dens;
    __syncthreads();
    for (int k = 2; k <= G_GR; k <<= 1) {
        for (int j = k >> 1; j > 0; j >>= 1) {
            int ixj = t ^ j;
            if (ixj > t) {
                float a = srt[t], b = srt[ixj];
                bool up = ((t & k) == 0);
                if ((a > b) == up) { srt[t] = b; srt[ixj] = a; }
            }
            __syncthreads();
        }
    }
    double p10 = 0.10 * 127.0, p90 = 0.90 * 127.0;
    int   i10 = (int)p10,           i90 = (int)p90;
    float f10 = (float)(p10 - i10), f90 = (float)(p90 - i90);
    float lo = srt[i10] + f10 * (srt[i10 + 1] - srt[i10]);
    float hi = srt[i90] + f90 * (srt[i90 + 1] - srt[i90]);
    dens = fminf(fmaxf(dens, lo), hi);

    red[t] = dens;
    __syncthreads();
    for (int s = 64; s > 0; s >>= 1) {
        if (t < s) red[t] += red[t + s];
        __syncthreads();
    }
    float dmean = red[0] / 128.f;
    __syncthreads();
    dens = 0.1f * dens / dmean;

    float cs = 0.f;
    for (int g = 0; g < G_GR; ++g) cs += centroid[g * D_DIM + t];
    coc[t] = cs / 128.f;
    __syncthreads();

    float dot = 0.f;
    for (int d = 0; d < D_DIM; ++d) dot += centroid[t * D_DIM + d] * coc[d];
    float sim = expf(dot / dens);

    red[t] = sim;
    __syncthreads();
    for (int s = 64; s > 0; s >>= 1) {
        if (t < s) red[t] = fmaxf(red[t], red[t + s]);
        __syncthreads();
    }
    float smax = red[0];
    __syncthreads();
    red[t] = sim - smax;
    __syncthreads();
    for (int s = 64; s > 0; s >>= 1) {
        if (t < s) red[t] += red[t + s];
        __syncthreads();
    }
    if (t == 0) out[0] = -(red[0] / 128.f);
}

// ---------------------------------------------------------------------------
extern "C" void kernel_launch(void* const* d_in, const int* in_sizes, int n_in,
                              void* d_out, int out_size, void* d_ws, size_t ws_size,
                              hipStream_t stream) {
    const float*  Xf      = (const float*)d_in[0];
    const int*    subject = (const int*)d_in[1];
    const int*    labels  = (const int*)d_in[2];
    float*        out     = (float*)d_out;
    char*         ws      = (char*)d_ws;

    size_t o = 0;
    float* cpart    = (float*)(ws + o); o += (size_t)NBLK * GD * 4;     // 32 MiB
    int*   hpart    = (int*)(ws + o);   o += (size_t)NBLK * G_GR * 4;   // 256 KiB
    float* centroid = (float*)(ws + o); o += (size_t)GD * 4;            // 64 KiB
    float* countsf  = (float*)(ws + o); o += 512;
    float* dpart    = (float*)(ws + o); o += (size_t)NBLK * G_GR * 4;   // 256 KiB
    float* dmid     = (float*)(ws + o); o += (size_t)DRB * G_GR * 4;    // 8 KiB

    k_centroid<<<NBLK, TPB, 0, stream>>>(Xf, subject, labels, cpart, hpart);
    k_reduce  <<<G_GR * 2, 512, 0, stream>>>(cpart, hpart, centroid, countsf);
    k_distn   <<<NBLK, TPB, 0, stream>>>(Xf, subject, labels, centroid, dpart);
    k_dred    <<<DRB, 256, 0, stream>>>(dpart, dmid);
    k_final   <<<1, 128, 0, stream>>>(dmid, countsf, centroid, out);
}

// Round 5
// 264.806 us; speedup vs baseline: 1.4359x; 1.0250x over previous
//
#include <hip/hip_runtime.h>
#include <cstdint>
#include <cstddef>

#define BPTS    131072
#define D_DIM   128
#define G_GR    128
#define NL      8
#define GD      (G_GR * D_DIM)       // 16384 floats = 64 KiB
#define NBLK    256                  // heavy-pass blocks: 1/CU
#define TPB     1024                 // 16 waves
#define PPB     (BPTS / NBLK)        // 512 contiguous points per block
#define GPW     (G_GR / (TPB / 64))  // 8 groups per wave

// d += dpp_shifted(d); pure VALU, no DS pipe.
__device__ __forceinline__ float dpp_add(float d, const int ctrl) {
    int s;
    switch (ctrl) {   // ctrl must be an ICE for the builtin
    case 0x111: s = __builtin_amdgcn_update_dpp(0, __float_as_int(d), 0x111, 0xf, 0xf, true); break;
    case 0x112: s = __builtin_amdgcn_update_dpp(0, __float_as_int(d), 0x112, 0xf, 0xf, true); break;
    case 0x114: s = __builtin_amdgcn_update_dpp(0, __float_as_int(d), 0x114, 0xf, 0xf, true); break;
    case 0x118: s = __builtin_amdgcn_update_dpp(0, __float_as_int(d), 0x118, 0xf, 0xf, true); break;
    case 0x142: s = __builtin_amdgcn_update_dpp(0, __float_as_int(d), 0x142, 0xf, 0xf, true); break;
    default:    s = __builtin_amdgcn_update_dpp(0, __float_as_int(d), 0x143, 0xf, 0xf, true); break;
    }
    return d + __int_as_float(s);
}

// full 64-lane sum -> result valid in lane 63
__device__ __forceinline__ float sum64(float d) {
    d = dpp_add(d, 0x111);
    d = dpp_add(d, 0x112);
    d = dpp_add(d, 0x114);
    d = dpp_add(d, 0x118);   // lane 15/31/47/63 hold 16-lane sums
    d = dpp_add(d, 0x142);   // lane 31/63 hold 32-lane sums
    d = dpp_add(d, 0x143);   // lane 63 holds 64-lane sum
    return d;
}

// ---------------------------------------------------------------------------
// k_centroid: builds per-block group bucket lists (hist + scan + scatter),
// persists them for k_distn, then group-major register accumulation:
// wave w owns 8 groups; per group, unroll-4 gather of bucketed points with
// coalesced float2 loads (lane l <-> dims 2l,2l+1), view-fold per-lane,
// float2 register accumulator, one coalesced store per group. Zero LDS
// atomics in the hot path.
// ---------------------------------------------------------------------------
__global__ __launch_bounds__(TPB) void k_centroid(const float* __restrict__ Xf,
                                                  const int* __restrict__ sub,
                                                  const int* __restrict__ lab,
                                                  float* __restrict__ cpart,
                                                  int* __restrict__ hpart,
                                                  int* __restrict__ goffG,
                                                  int* __restrict__ glistG) {
    __shared__ int glist[PPB];
    __shared__ int goff[G_GR];
    __shared__ int hist[G_GR];
    __shared__ int cursor[G_GR];
    __shared__ int scan[G_GR];
    int t = threadIdx.x, blk = blockIdx.x;
    int lane = t & 63, w = t >> 6;
    int pbase = blk * PPB;

    // ---- build bucket lists ----
    if (t < G_GR) hist[t] = 0;
    __syncthreads();
    int myg = -1;
    if (t < PPB) {
        myg = sub[pbase + t] * NL + lab[pbase + t];
        atomicAdd(&hist[myg], 1);
    }
    __syncthreads();
    if (t < G_GR) scan[t] = hist[t];
    __syncthreads();
    for (int s = 1; s < G_GR; s <<= 1) {
        int v = 0;
        if (t < G_GR) { v = scan[t]; if (t >= s) v += scan[t - s]; }
        __syncthreads();
        if (t < G_GR) scan[t] = v;
        __syncthreads();
    }
    if (t < G_GR) { goff[t] = scan[t] - hist[t]; cursor[t] = scan[t] - hist[t]; }
    __syncthreads();
    if (t < PPB) {
        int pos = atomicAdd(&cursor[myg], 1);
        glist[pos] = t;
    }
    __syncthreads();

    // persist for k_distn
    if (t < G_GR) {
        hpart[blk * G_GR + t] = hist[t];
        goffG[blk * G_GR + t] = goff[t];
    }
    if (t < PPB) glistG[blk * PPB + t] = glist[t];

    // ---- group-major accumulate ----
    for (int gi = 0; gi < GPW; ++gi) {
        int g = w * GPW + gi;
        int s = goff[g], n = hist[g];
        float ax = 0.f, ay = 0.f;
        int k = 0;
        for (; k + 4 <= n; k += 4) {                 // 8 loads in flight
            int p0 = pbase + glist[s + k + 0];
            int p1 = pbase + glist[s + k + 1];
            int p2 = pbase + glist[s + k + 2];
            int p3 = pbase + glist[s + k + 3];
            const float* r0 = Xf + (size_t)p0 * 256;
            const float* r1 = Xf + (size_t)p1 * 256;
            const float* r2 = Xf + (size_t)p2 * 256;
            const float* r3 = Xf + (size_t)p3 * 256;
            float2 a0 = *(const float2*)(r0 + 2 * lane);
            float2 b0 = *(const float2*)(r0 + 128 + 2 * lane);
            float2 a1 = *(const float2*)(r1 + 2 * lane);
            float2 b1 = *(const float2*)(r1 + 128 + 2 * lane);
            float2 a2 = *(const float2*)(r2 + 2 * lane);
            float2 b2 = *(const float2*)(r2 + 128 + 2 * lane);
            float2 a3 = *(const float2*)(r3 + 2 * lane);
            float2 b3 = *(const float2*)(r3 + 128 + 2 * lane);
            ax += (a0.x + b0.x) + (a1.x + b1.x) + (a2.x + b2.x) + (a3.x + b3.x);
            ay += (a0.y + b0.y) + (a1.y + b1.y) + (a2.y + b2.y) + (a3.y + b3.y);
        }
        for (; k < n; ++k) {
            int p = pbase + glist[s + k];
            const float* r = Xf + (size_t)p * 256;
            float2 a = *(const float2*)(r + 2 * lane);
            float2 b = *(const float2*)(r + 128 + 2 * lane);
            ax += a.x + b.x;
            ay += a.y + b.y;
        }
        float2 o; o.x = ax; o.y = ay;
        *(float2*)(cpart + (size_t)blk * GD + (size_t)g * D_DIM + 2 * lane) = o;
    }
}

// ---------------------------------------------------------------------------
// k_reduce: centroid[g][d] = sum_b cpart[b][g][d] / (2n). 256 blocks:
// block = (g, half-of-D). 4 independent accumulators for MLP.
// ---------------------------------------------------------------------------
__global__ __launch_bounds__(512) void k_reduce(const float* __restrict__ cpart,
                                                const int* __restrict__ hpart,
                                                float* __restrict__ centroid,
                                                float* __restrict__ countsf) {
    __shared__ float red[8][64];
    __shared__ int   hred[64];
    __shared__ float cf2s;
    int g = blockIdx.x >> 1, h = blockIdx.x & 1;
    int t = threadIdx.x;
    int dl = t & 63, bs = t >> 6;             // 8 b-slices x 64 lanes
    int d = h * 64 + dl;

    float a0 = 0.f, a1 = 0.f, a2 = 0.f, a3 = 0.f;
    for (int b = bs; b < NBLK; b += 32) {     // 4 loads in flight
        a0 += cpart[(size_t)(b)      * GD + g * D_DIM + d];
        a1 += cpart[(size_t)(b + 8)  * GD + g * D_DIM + d];
        a2 += cpart[(size_t)(b + 16) * GD + g * D_DIM + d];
        a3 += cpart[(size_t)(b + 24) * GD + g * D_DIM + d];
    }
    red[bs][dl] = (a0 + a1) + (a2 + a3);

    if (t < 64) {
        int hacc = 0;
        for (int b = t; b < NBLK; b += 64) hacc += hpart[b * G_GR + g];
        hred[t] = hacc;
    }
    __syncthreads();
    if (t == 0) {
        int n = 0;
        for (int i = 0; i < 64; ++i) n += hred[i];
        cf2s = 2.f * (float)n;
        if (h == 0) countsf[g] = cf2s;
    }
    __syncthreads();
    if (t < 64) {
        float v = 0.f;
#pragma unroll
        for (int r = 0; r < 8; ++r) v += red[r][t];
        float cf2 = cf2s;
        centroid[g * D_DIM + h * 64 + t] = (cf2 > 0.f) ? v / cf2 : 0.f;
    }
}

// ---------------------------------------------------------------------------
// k_distn: reloads the persisted bucket lists (no rebuild). Centroid row
// loaded once per group; per point: 2 coalesced float2 loads, two
// independent 64-lane DPP sums (VALU pipe), unroll-2 across points;
// sqrt(sqrt()) accumulated in lane 63's register; one store per group.
// ---------------------------------------------------------------------------
__global__ __launch_bounds__(TPB) void k_distn(const float* __restrict__ Xf,
                                               const int* __restrict__ hpart,
                                               const int* __restrict__ goffG,
                                               const int* __restrict__ glistG,
                                               const float* __restrict__ centroid,
                                               float* __restrict__ dpart) {
    __shared__ int glist[PPB];
    __shared__ int goff[G_GR];
    __shared__ int hist[G_GR];
    int t = threadIdx.x, blk = blockIdx.x;
    int lane = t & 63, w = t >> 6;
    int pbase = blk * PPB;

    if (t < G_GR) {
        hist[t] = hpart[blk * G_GR + t];
        goff[t] = goffG[blk * G_GR + t];
    }
    if (t < PPB) glist[t] = glistG[blk * PPB + t];
    __syncthreads();

    for (int gi = 0; gi < GPW; ++gi) {
        int g = w * GPW + gi;
        int s = goff[g], n = hist[g];
        float2 c = *(const float2*)(centroid + (size_t)g * D_DIM + 2 * lane);
        float sacc = 0.f;
        int k = 0;
        for (; k + 2 <= n; k += 2) {          // two independent DPP chains
            int p0 = pbase + glist[s + k];
            int p1 = pbase + glist[s + k + 1];
            const float* r0 = Xf + (size_t)p0 * 256;
            const float* r1 = Xf + (size_t)p1 * 256;
            float2 a0 = *(const float2*)(r0 + 2 * lane);
            float2 b0 = *(const float2*)(r0 + 128 + 2 * lane);
            float2 a1 = *(const float2*)(r1 + 2 * lane);
            float2 b1 = *(const float2*)(r1 + 128 + 2 * lane);
            float e0 = a0.x - c.x, e1 = a0.y - c.y;
            float f0 = b0.x - c.x, f1 = b0.y - c.y;
            float g0 = a1.x - c.x, g1 = a1.y - c.y;
            float h0 = b1.x - c.x, h1 = b1.y - c.y;
            float d0 = sum64(e0 * e0 + e1 * e1);
            float d1 = sum64(f0 * f0 + f1 * f1);
            float d2 = sum64(g0 * g0 + g1 * g1);
            float d3 = sum64(h0 * h0 + h1 * h1);
            sacc += (sqrtf(sqrtf(d0)) + sqrtf(sqrtf(d1)))
                  + (sqrtf(sqrtf(d2)) + sqrtf(sqrtf(d3)));
        }
        if (k < n) {
            int p = pbase + glist[s + k];
            const float* r = Xf + (size_t)p * 256;
            float2 a = *(const float2*)(r + 2 * lane);
            float2 b = *(const float2*)(r + 128 + 2 * lane);
            float e0 = a.x - c.x, e1 = a.y - c.y;
            float f0 = b.x - c.x, f1 = b.y - c.y;
            float d0 = sum64(e0 * e0 + e1 * e1);
            float d1 = sum64(f0 * f0 + f1 * f1);
            sacc += sqrtf(sqrtf(d0)) + sqrtf(sqrtf(d1));
        }
        if (lane == 63) dpart[blk * G_GR + g] = sacc;    // valid in lane 63
    }
}

// ---------------------------------------------------------------------------
// k_final: single block, 512 threads. Folds dpart (256x128) itself,
// percentile/clip on t<128, coc via 4-slice coalesced reduce, dot via
// 8 waves x DPP sum64 (no uncoalesced row walk).
// ---------------------------------------------------------------------------
__global__ __launch_bounds__(512) void k_final(const float* __restrict__ dpart,
                                               const float* __restrict__ countsf,
                                               const float* __restrict__ centroid,
                                               float* __restrict__ out) {
    __shared__ float sl4[4][G_GR];
    __shared__ float srt[G_GR];
    __shared__ float red[G_GR];
    __shared__ float cocs[D_DIM];
    __shared__ float dotv[G_GR];
    __shared__ float densv[G_GR];
    int t = threadIdx.x;
    int col = t & 127, q = t >> 7;            // 4 slices
    int lane = t & 63, w8 = t >> 6;           // 8 waves

    // 1) dpart reduction (256 rows x 128) with MLP
    float a0 = 0.f, a1 = 0.f;
    for (int b = q; b < NBLK; b += 8) {
        a0 += dpart[(b)     * G_GR + col];
        a1 += dpart[(b + 4) * G_GR + col];
    }
    sl4[q][col] = a0 + a1;
    __syncthreads();

    float dens = 0.f, cnt = 0.f;
    if (t < G_GR) {
        float ds = sl4[0][t] + sl4[1][t] + sl4[2][t] + sl4[3][t];
        cnt = countsf[t];
        dens = (cnt > 1.f) ? (ds / cnt) / logf(cnt + 10.f) : 0.f;
        red[t] = dens;
    }
    __syncthreads();
    for (int s = 64; s > 0; s >>= 1) {
        if (t < s) red[t] = fmaxf(red[t], red[t + s]);
        __syncthreads();
    }
    float dmax = red[0];
    __syncthreads();
    if (t < G_GR && !(cnt > 1.f)) dens = dmax;

    // bitonic sort ascending over 128 entries
    if (t < G_GR) srt[t] = dens;
    __syncthreads();
    for (int k = 2; k <= G_GR; k <<= 1) {
        for (int j = k >> 1; j > 0; j >>= 1) {
            int ixj = t ^ j;
            if (t < G_GR && ixj > t) {
                float a = srt[t], b = srt[ixj];
                bool up = ((t & k) == 0);
                if ((a > b) == up) { srt[t] = b; srt[ixj] = a; }
            }
            __syncthreads();
        }
    }
    double p10 = 0.10 * 127.0, p90 = 0.90 * 127.0;
    int   i10 = (int)p10,           i90 = (int)p90;
    float f10 = (float)(p10 - i10), f90 = (float)(p90 - i90);
    float lo = srt[i10] + f10 * (srt[i10 + 1] - srt[i10]);
    float hi = srt[i90] + f90 * (srt[i90 + 1] - srt[i90]);
    if (t < G_GR) dens = fminf(fmaxf(dens, lo), hi);

    if (t < G_GR) red[t] = dens;
    __syncthreads();
    for (int s = 64; s > 0; s >>= 1) {
        if (t < s) red[t] += red[t + s];
        __syncthreads();
    }
    float dmean = red[0] / 128.f;
    __syncthreads();
    if (t < G_GR) densv[t] = 0.1f * dens / dmean;

    // coc: 4-slice coalesced column sum
    float cs = 0.f;
    for (int g = q; g < G_GR; g += 4) cs += centroid[g * D_DIM + col];
    sl4[q][col] = cs;
    __syncthreads();
    if (t < D_DIM)
        cocs[t] = (sl4[0][t] + sl4[1][t] + sl4[2][t] + sl4[3][t]) / 128.f;
    __syncthreads();

    // dot: 8 waves x 16 groups, DPP sum64 per group (coalesced loads)
    {
        float2 co = *(const float2*)&cocs[2 * lane];
        for (int i = 0; i < 16; ++i) {
            int g = w8 * 16 + i;
            float2 c = *(const float2*)(centroid + (size_t)g * D_DIM + 2 * lane);
            float p = c.x * co.x + c.y * co.y;
            float s = sum64(p);
            if (lane == 63) dotv[g] = s;
        }
    }
    __syncthreads();

    float sim = 0.f;
    if (t < G_GR) {
        sim = expf(dotv[t] / densv[t]);
        red[t] = sim;
    }
    __syncthreads();
    for (int s = 64; s > 0; s >>= 1) {
        if (t < s) red[t] = fmaxf(red[t], red[t + s]);
        __syncthreads();
    }
    float smax = red[0];
    __syncthreads();
    if (t < G_GR) red[t] = sim - smax;
    __syncthreads();
    for (int s = 64; s > 0; s >>= 1) {
        if (t < s) red[t] += red[t + s];
        __syncthreads();
    }
    if (t == 0) out[0] = -(red[0] / 128.f);
}

// ---------------------------------------------------------------------------
extern "C" void kernel_launch(void* const* d_in, const int* in_sizes, int n_in,
                              void* d_out, int out_size, void* d_ws, size_t ws_size,
                              hipStream_t stream) {
    const float*  Xf      = (const float*)d_in[0];
    const int*    subject = (const int*)d_in[1];
    const int*    labels  = (const int*)d_in[2];
    float*        out     = (float*)d_out;
    char*         ws      = (char*)d_ws;

    size_t o = 0;
    float* cpart    = (float*)(ws + o); o += (size_t)NBLK * GD * 4;     // 16 MiB
    int*   hpart    = (int*)(ws + o);   o += (size_t)NBLK * G_GR * 4;   // 128 KiB
    int*   goffG    = (int*)(ws + o);   o += (size_t)NBLK * G_GR * 4;   // 128 KiB
    int*   glistG   = (int*)(ws + o);   o += (size_t)NBLK * PPB * 4;    // 512 KiB
    float* centroid = (float*)(ws + o); o += (size_t)GD * 4;            // 64 KiB
    float* countsf  = (float*)(ws + o); o += 512;
    float* dpart    = (float*)(ws + o); o += (size_t)NBLK * G_GR * 4;   // 128 KiB

    k_centroid<<<NBLK, TPB, 0, stream>>>(Xf, subject, labels, cpart, hpart, goffG, glistG);
    k_reduce  <<<G_GR * 2, 512, 0, stream>>>(cpart, hpart, centroid, countsf);
    k_distn   <<<NBLK, TPB, 0, stream>>>(Xf, hpart, goffG, glistG, centroid, dpart);
    k_final   <<<1, 512, 0, stream>>>(dpart, countsf, centroid, out);
}